// Round 24
// baseline (93.920 us; speedup 1.0000x reference)
//
#include <hip/hip_runtime.h>
#include <hip/hip_bf16.h>
#include <stdint.h>

// Problem constants
#define NB    32    // batch
#define CIN   128
#define HH    56
#define WW    56
#define COUT  256
#define NT    (NB * HH)   // 1792 output tiles (b, oh)

// ws layout: wpack (bf16, 36*8192 = 294,912 elems = 589,824 B), then counter
typedef __attribute__((ext_vector_type(4))) float f32x4;
typedef __attribute__((ext_vector_type(8))) short bf16x8;

__device__ __forceinline__ unsigned short f2bf(float f) {
    union { float f; unsigned u; } v; v.f = f;
    unsigned r = v.u + 0x7FFFu + ((v.u >> 16) & 1u);
    return (unsigned short)(r >> 16);
}

// ---------------------------------------------------------------------------
// build_weight: compose per-output-channel filters.
// wpack layout (R13-verified): [tile(36)][wid(4)][mf(4)][lane(64)][kin(8)]
//   elem = tile*8192 + wid*2048 + mf*512 + lane*8 + kin; tile = pos*4+cib,
//   o = wid*64+mf*16+fl, lane = kpos*16+fl, ci = cib*32+kpos*8+kin.
// ---------------------------------------------------------------------------
__global__ __launch_bounds__(256) void build_weight(
    const float* __restrict__ dict, const float* __restrict__ coef,
    const int* __restrict__ idxw, unsigned short* __restrict__ wpack) {
    int o = blockIdx.x;
    int tid = threadIdx.x;
    bool mode64 = (idxw[1] == 0) && (idxw[3] == 0) && (idxw[5] == 0) &&
                  (idxw[7] == 0) && (idxw[9] == 0) && (idxw[11] == 0) &&
                  (idxw[13] == 0) && (idxw[15] == 0);
    float c[8]; int di[8];
#pragma unroll
    for (int s = 0; s < 8; ++s) {
        c[s]  = coef[o * 8 + s];
        di[s] = mode64 ? idxw[(o * 8 + s) * 2] : idxw[o * 8 + s];
    }
    const int wid = o >> 6, mf = (o >> 4) & 3, fl = o & 15;
    for (int j = tid; j < 9 * 128; j += 256) {
        int pos = j >> 7;          // 0..8
        int ci  = j & 127;
        int kh = pos / 3, kw = pos - kh * 3;
        float v = 0.f;
#pragma unroll
        for (int s = 0; s < 8; ++s)
            v += c[s] * dict[((di[s] * CIN + ci) * 3 + kh) * 3 + kw];
        int tile = pos * 4 + (ci >> 5);
        int kpos = (ci >> 3) & 3, kin = ci & 7;
        wpack[tile * 8192 + wid * 2048 + mf * 512 + (kpos * 16 + fl) * 8 + kin]
            = f2bf(v);
    }
}

// ---------------------------------------------------------------------------
// Main: FUSED pack + implicit-GEMM conv (R24 = R19 + dynamic tile grab).
// R23 confirmed R19's 78.2us reproduces; the remaining identified loss is
// grid quantization: 1792 blocks / 3-per-CU = rounds of 3+3+1, the final
// round at 1 block/CU with per-wave latency fully exposed (~10-20%).
// R24: launch exactly 768 blocks (3/CU); each grabs tiles from a global
// atomic counter until NT=1792 are done. Tail shrinks to ~1 tile (~0.5us).
// Per-tile body = R19 verbatim (verified: batched pack, stride-512 slab,
// one barrier, ping-pong A, 0-conflict reads). The tile-fetch barrier
// doubles as the slab-overwrite guard. Deterministic output: tiles are
// independent; assignment order never changes values.
//  - (256,3): LDS 49.7 KB -> 3 blocks/CU; ~85 arch + 64 AGPR, no spill.
// ---------------------------------------------------------------------------
__global__ __launch_bounds__(256, 3) void conv_mfma(
    const float* __restrict__ x,
    const unsigned short* __restrict__ wpack,
    float* __restrict__ out,
    int* __restrict__ counter) {
    // slab: elem = (row*16 + ch)*512 + iw*8 + kin ; +128 pad (junk-col reads)
    __shared__ unsigned short Bl[3 * 16 * 512 + 128];
    __shared__ int sTau;

    int tid  = threadIdx.x;
    int lane = tid & 63;
    int wid  = tid >> 6;       // 0..3 = Cout slice of 64 (and ci-quarter in pack)

    const int klane = lane >> 4;   // k-group (0..3)
    const int fl    = lane & 15;

    // A-fragment base (coalesced): af(tile,mf) = ap0 + tile*8192 + mf*512 elems
    const unsigned short* ap0 = wpack + (size_t)wid * 2048 + lane * 8;

    // pack-lane geometry (lane = iw)
    const int iw = lane;
    const bool vw = (iw >= 1) && (iw <= WW);
    const int w = vw ? iw - 1 : 0;

    for (;;) {
        // ---- grab next tile; barrier also guards slab overwrite ----
        if (tid == 0) sTau = atomicAdd(counter, 1);
        __syncthreads();
        const int tau = sTau;
        if (tau >= NT) break;
        const int b  = tau / HH;
        const int oh = tau % HH;

        // ---- issue A(tile 0) early: latency hides under the pack phase ----
        bf16x8 af[2][4];
#pragma unroll
        for (int mf = 0; mf < 4; ++mf)
            af[0][mf] = *(const bf16x8*)(ap0 + mf * 512);

        // ---- fused pack: lane = iw, wave = ci-quarter; batched loads ----
#pragma unroll
        for (int row = 0; row < 3; ++row) {
            int h = oh + row - 1;
            bool valid = vw && (h >= 0) && (h < HH);
            int hc = h < 0 ? 0 : (h >= HH ? HH - 1 : h);
            const float* px =
                x + (((size_t)b * CIN + wid * 32) * HH + hc) * WW + w;
            float v[32];
#pragma unroll
            for (int j = 0; j < 32; ++j)          // 32 independent loads
                v[j] = px[(size_t)j * (HH * WW)];
#pragma unroll
            for (int c = 0; c < 4; ++c) {         // one wait, 4 vector writes
                bf16x8 pv;
#pragma unroll
                for (int j = 0; j < 8; ++j)
                    pv[j] = valid ? (short)f2bf(v[c * 8 + j]) : (short)0;
                *(bf16x8*)&Bl[(row * 16 + wid * 4 + c) * 512 + iw * 8] = pv;
            }
        }

        f32x4 acc[4][4];
        f32x4 zero = {0.f, 0.f, 0.f, 0.f};
#pragma unroll
        for (int i = 0; i < 4; ++i)
#pragma unroll
            for (int j = 0; j < 4; ++j) acc[i][j] = zero;

        __syncthreads();   // slab resident

        const unsigned short* apc = ap0;                       // += 8192/cib
        const unsigned short* bl0 = &Bl[klane * 512 + fl * 8];

#pragma unroll 2
        for (int cib = 0; cib < 4; ++cib) {
            const unsigned short* bcur = bl0 + cib * 2048;     // 4 ch per cib

#pragma unroll
            for (int pos = 0; pos < 9; ++pos) {
                const int kh = pos / 3, kw = pos - kh * 3;
                const int cur = (cib + pos) & 1;   // STATIC under unroll-2 cib

                // ---- prefetch A(next step) into the free set (ping-pong) ----
                if (pos < 8) {
#pragma unroll
                    for (int mf = 0; mf < 4; ++mf)
                        af[cur ^ 1][mf] =
                            *(const bf16x8*)(apc + (pos + 1) * 32768 + mf * 512);
                } else if (cib < 3) {
#pragma unroll
                    for (int mf = 0; mf < 4; ++mf)
                        af[cur ^ 1][mf] = *(const bf16x8*)(apc + 8192 + mf * 512);
                }

                // ---- B fragments from resident slab (imm-offset ds_read) ----
                bf16x8 bfr[4];
#pragma unroll
                for (int nf = 0; nf < 4; ++nf)
                    bfr[nf] = *(const bf16x8*)(bcur + kh * 8192 + (nf * 16 + kw) * 8);

                // ---- 16 MFMA on af[cur] (loaded a full step ago) ----
                __builtin_amdgcn_s_setprio(1);
#pragma unroll
                for (int mf = 0; mf < 4; ++mf)
#pragma unroll
                    for (int nf = 0; nf < 4; ++nf)
                        acc[mf][nf] = __builtin_amdgcn_mfma_f32_16x16x32_bf16(
                            af[cur][mf], bfr[nf], acc[mf][nf], 0, 0, 0);
                __builtin_amdgcn_s_setprio(0);
            }
            apc += 8192;
        }

        // Epilogue: C/D layout col = lane&15, row = (lane>>4)*4 + reg
#pragma unroll
        for (int nf = 0; nf < 4; ++nf) {
            int ow = nf * 16 + fl;
            if (ow < WW) {
#pragma unroll
                for (int mf = 0; mf < 4; ++mf) {
                    int ob = wid * 64 + mf * 16 + (lane >> 4) * 4;
                    float* dst = out + (((size_t)b * COUT + ob) * HH + oh) * WW + ow;
#pragma unroll
                    for (int r = 0; r < 4; ++r)
                        dst[(size_t)r * HH * WW] = acc[mf][nf][r];
                }
            }
        }
    }
}

extern "C" void kernel_launch(void* const* d_in, const int* in_sizes, int n_in,
                              void* d_out, int out_size, void* d_ws, size_t ws_size,
                              hipStream_t stream) {
    const float* x    = (const float*)d_in[0];
    const float* dict = (const float*)d_in[1];
    const float* coef = (const float*)d_in[2];
    const int*   idxw = (const int*)d_in[3];
    float* out = (float*)d_out;

    unsigned short* wpack = (unsigned short*)d_ws;
    int* counter = (int*)((char*)d_ws + 36 * 8192 * sizeof(unsigned short));

    hipMemsetAsync(counter, 0, sizeof(int), stream);   // reset each call
    build_weight<<<dim3(COUT), dim3(256), 0, stream>>>(dict, coef, idxw, wpack);
    conv_mfma<<<dim3(768), dim3(256), 0, stream>>>(x, wpack, out, counter);
}

// Round 25
// 78.744 us; speedup vs baseline: 1.1927x; 1.1927x over previous
//
#include <hip/hip_runtime.h>
#include <hip/hip_bf16.h>
#include <stdint.h>

// Problem constants
#define NB    32    // batch
#define CIN   128
#define HH    56
#define WW    56
#define COUT  256

// ws layout: wpack only (bf16, 36*8192 = 294,912 elems)
typedef __attribute__((ext_vector_type(4))) float f32x4;
typedef __attribute__((ext_vector_type(8))) short bf16x8;

__device__ __forceinline__ unsigned short f2bf(float f) {
    union { float f; unsigned u; } v; v.f = f;
    unsigned r = v.u + 0x7FFFu + ((v.u >> 16) & 1u);
    return (unsigned short)(r >> 16);
}

// ---------------------------------------------------------------------------
// build_weight: compose per-output-channel filters.
// wpack layout (R13-verified): [tile(36)][wid(4)][mf(4)][lane(64)][kin(8)]
//   elem = tile*8192 + wid*2048 + mf*512 + lane*8 + kin; tile = pos*4+cib,
//   o = wid*64+mf*16+fl, lane = kpos*16+fl, ci = cib*32+kpos*8+kin.
// ---------------------------------------------------------------------------
__global__ __launch_bounds__(256) void build_weight(
    const float* __restrict__ dict, const float* __restrict__ coef,
    const int* __restrict__ idxw, unsigned short* __restrict__ wpack) {
    int o = blockIdx.x;
    int tid = threadIdx.x;
    bool mode64 = (idxw[1] == 0) && (idxw[3] == 0) && (idxw[5] == 0) &&
                  (idxw[7] == 0) && (idxw[9] == 0) && (idxw[11] == 0) &&
                  (idxw[13] == 0) && (idxw[15] == 0);
    float c[8]; int di[8];
#pragma unroll
    for (int s = 0; s < 8; ++s) {
        c[s]  = coef[o * 8 + s];
        di[s] = mode64 ? idxw[(o * 8 + s) * 2] : idxw[o * 8 + s];
    }
    const int wid = o >> 6, mf = (o >> 4) & 3, fl = o & 15;
    for (int j = tid; j < 9 * 128; j += 256) {
        int pos = j >> 7;          // 0..8
        int ci  = j & 127;
        int kh = pos / 3, kw = pos - kh * 3;
        float v = 0.f;
#pragma unroll
        for (int s = 0; s < 8; ++s)
            v += c[s] * dict[((di[s] * CIN + ci) * 3 + kh) * 3 + kw];
        int tile = pos * 4 + (ci >> 5);
        int kpos = (ci >> 3) & 3, kin = ci & 7;
        wpack[tile * 8192 + wid * 2048 + mf * 512 + (kpos * 16 + fl) * 8 + kin]
            = f2bf(v);
    }
}

// ---------------------------------------------------------------------------
// Main: FUSED pack + implicit-GEMM conv (R25 = R19 verbatim, the verified
// best: 78.28us R19, 78.19us R23). Session map: 9 structural hypotheses
// (barrier removal R8, B-reg-pipelining R10, A-bandwidth R11, A-coalescing
// R13, mov-rotation R15, occupancy up R18 / down R11, pack-hiding R20/R21,
// 32x32 MFMA R22, dynamic tiles R24) — all null or negative. Conv ~1000 TF
// = 49% of the 16x16 MFMA ceiling at 3 waves/SIMD: the plain-HIP plateau
// for this structure class (8-phase escape closed: 64-AGPR acc x 8-wave
// blocks exceeds the 512 unified regs/SIMD budget — R18).
//  - fused batched pack: lane = iw, wave = ci-quarter; 32 independent
//    loads -> one wait -> 4 conflict-free 16B LDS writes (R16/R17 lessons:
//    stride 512 for reads; lane=iw for writes; batched loads).
//  - slab [row(3)][ch(16)][iw(64)][kin(8)] stride 512, 0-conflict reads,
//    resident for the whole K-loop: ONE barrier per block (R14).
//  - A: direct global->reg from L2-hot wpack (R13 coalesced layout),
//    ping-pong sets, static index under unroll-2 cib (R15).
//  - XCD-bijective block swizzle (R24 lesson: losing it doubles FETCH).
//  - (256,3): LDS 49.7 KB -> 3 blocks/CU; 80 arch + 64 AGPR, no spill.
// ---------------------------------------------------------------------------
__global__ __launch_bounds__(256, 3) void conv_mfma(
    const float* __restrict__ x,
    const unsigned short* __restrict__ wpack,
    float* __restrict__ out) {
    // slab: elem = (row*16 + ch)*512 + iw*8 + kin ; +128 pad (junk-col reads)
    __shared__ unsigned short Bl[3 * 16 * 512 + 128];

    int tid  = threadIdx.x;
    int lane = tid & 63;
    int wid  = tid >> 6;       // 0..3 = Cout slice of 64 (and ci-quarter in pack)

    // XCD-bijective swizzle: 1792 = 8 * 224; each XCD gets 4 consecutive b's
    int flat = blockIdx.x;
    int swz  = (flat & 7) * 224 + (flat >> 3);
    int b    = swz / 56;       // 0..31
    int oh   = swz % 56;       // output row

    const int klane = lane >> 4;   // k-group (0..3)
    const int fl    = lane & 15;

    // A-fragment base (coalesced): af(tile,mf) = ap0 + tile*8192 + mf*512 elems
    const unsigned short* ap0 = wpack + (size_t)wid * 2048 + lane * 8;

    // ---- issue A(tile 0) early: latency hides under the pack phase ----
    bf16x8 af[2][4];
#pragma unroll
    for (int mf = 0; mf < 4; ++mf)
        af[0][mf] = *(const bf16x8*)(ap0 + mf * 512);

    // ---- fused pack: lane = iw, wave = ci-quarter; batched 32-float loads ----
    {
        const int iw = lane;
        const bool vw = (iw >= 1) && (iw <= WW);
        const int w = vw ? iw - 1 : 0;
#pragma unroll
        for (int row = 0; row < 3; ++row) {
            int h = oh + row - 1;
            bool valid = vw && (h >= 0) && (h < HH);
            int hc = h < 0 ? 0 : (h >= HH ? HH - 1 : h);
            const float* px =
                x + (((size_t)b * CIN + wid * 32) * HH + hc) * WW + w;
            float v[32];
#pragma unroll
            for (int j = 0; j < 32; ++j)          // 32 independent loads
                v[j] = px[(size_t)j * (HH * WW)];
#pragma unroll
            for (int c = 0; c < 4; ++c) {         // one wait, 4 vector writes
                bf16x8 pv;
#pragma unroll
                for (int j = 0; j < 8; ++j)
                    pv[j] = valid ? (short)f2bf(v[c * 8 + j]) : (short)0;
                *(bf16x8*)&Bl[(row * 16 + wid * 4 + c) * 512 + iw * 8] = pv;
            }
        }
    }

    f32x4 acc[4][4];
    f32x4 zero = {0.f, 0.f, 0.f, 0.f};
#pragma unroll
    for (int i = 0; i < 4; ++i)
#pragma unroll
        for (int j = 0; j < 4; ++j) acc[i][j] = zero;

    __syncthreads();   // slab resident; ONLY barrier in the kernel

    const unsigned short* apc = ap0;                       // += 8192/cib
    const unsigned short* bl0 = &Bl[klane * 512 + fl * 8];

#pragma unroll 2
    for (int cib = 0; cib < 4; ++cib) {
        const unsigned short* bcur = bl0 + cib * 2048;     // 4 ch per cib

#pragma unroll
        for (int pos = 0; pos < 9; ++pos) {
            const int kh = pos / 3, kw = pos - kh * 3;
            const int cur = (cib + pos) & 1;   // STATIC under unroll-2 cib

            // ---- prefetch A(next step) into the free set (ping-pong) ----
            if (pos < 8) {
#pragma unroll
                for (int mf = 0; mf < 4; ++mf)
                    af[cur ^ 1][mf] =
                        *(const bf16x8*)(apc + (pos + 1) * 32768 + mf * 512);
            } else if (cib < 3) {
#pragma unroll
                for (int mf = 0; mf < 4; ++mf)
                    af[cur ^ 1][mf] = *(const bf16x8*)(apc + 8192 + mf * 512);
            }

            // ---- B fragments from resident slab (imm-offset ds_read) ----
            bf16x8 bfr[4];
#pragma unroll
            for (int nf = 0; nf < 4; ++nf)
                bfr[nf] = *(const bf16x8*)(bcur + kh * 8192 + (nf * 16 + kw) * 8);

            // ---- 16 MFMA on af[cur] (loaded a full step ago) ----
            __builtin_amdgcn_s_setprio(1);
#pragma unroll
            for (int mf = 0; mf < 4; ++mf)
#pragma unroll
                for (int nf = 0; nf < 4; ++nf)
                    acc[mf][nf] = __builtin_amdgcn_mfma_f32_16x16x32_bf16(
                        af[cur][mf], bfr[nf], acc[mf][nf], 0, 0, 0);
            __builtin_amdgcn_s_setprio(0);
        }
        apc += 8192;
    }

    // Epilogue: C/D layout col = lane&15, row = (lane>>4)*4 + reg (m89-verified)
#pragma unroll
    for (int nf = 0; nf < 4; ++nf) {
        int ow = nf * 16 + fl;
        if (ow < WW) {
#pragma unroll
            for (int mf = 0; mf < 4; ++mf) {
                int ob = wid * 64 + mf * 16 + (lane >> 4) * 4;
                float* dst = out + (((size_t)b * COUT + ob) * HH + oh) * WW + ow;
#pragma unroll
                for (int r = 0; r < 4; ++r)
                    dst[(size_t)r * HH * WW] = acc[mf][nf][r];
            }
        }
    }
}

extern "C" void kernel_launch(void* const* d_in, const int* in_sizes, int n_in,
                              void* d_out, int out_size, void* d_ws, size_t ws_size,
                              hipStream_t stream) {
    const float* x    = (const float*)d_in[0];
    const float* dict = (const float*)d_in[1];
    const float* coef = (const float*)d_in[2];
    const int*   idxw = (const int*)d_in[3];
    float* out = (float*)d_out;

    unsigned short* wpack = (unsigned short*)d_ws;

    build_weight<<<dim3(COUT), dim3(256), 0, stream>>>(dict, coef, idxw, wpack);
    conv_mfma<<<dim3(NB * 56), dim3(256), 0, stream>>>(x, wpack, out);
}